// Round 10
// baseline (232.850 us; speedup 1.0000x reference)
//
#include <hip/hip_runtime.h>
#include <hip/hip_bf16.h>

// Shapes: bz=32, rv_num=10, rv_len=128, in_feat=300, out_feat=128
// N = 320 reviews/side, tokens/side = 40960, M = 1280 tokens/sample.
// Fused design: block n == review n (side = n/320). After the fc K-loop the
// block holds its review's 128x128 fp32 tile in registers; only the other
// side's sample-mean crosses blocks -> psum + software grid barrier, then
// softmax + weighted sum directly from registers. ta/tb never materialize.
// Barrier safety: 24.6 KB LDS + launch_bounds(256,3) => >=3 blocks/CU =>
// 768 >= 640 all co-resident; barrier counter is monotonic (no re-arm).

#define K_FEAT 300
#define H 128
#define NREV 320
#define TOK_PER_SAMPLE 1280
#define TM 128
#define LDA 40                      // LDS row stride in bf16 (32 k + 8 pad)
#define NCHUNK 10
#define WFRAG_ELEMS (NCHUNK * 4 * 4 * 64 * 8)   // 81920 bf16 = 160 KB
#define NBLOCKS (2 * NREV)          // 640

typedef __attribute__((ext_vector_type(8))) short bf16x8;
typedef __attribute__((ext_vector_type(4))) float f32x4;
typedef unsigned short u16;
typedef unsigned int u32;

static __device__ __forceinline__ u16 f2bf(float x) {
    u32 u = __float_as_uint(x);
    return (u16)((u + 0x7fffu + ((u >> 16) & 1u)) >> 16);
}
static __device__ __forceinline__ float bf2f(u16 s) {
    return __uint_as_float(((u32)s) << 16);
}

// ---------------- Kernel 0a: zero the barrier counter ----------------
__global__ void bar_init_kernel(u32* __restrict__ bar)
{
    if (threadIdx.x == 0) *bar = 0u;
}

// ---------------- Kernel 0b: pack W into per-(chunk,wave,frag,lane) bf16 fragments --------
// Wfrag[c][wave][frag][lane][8]; frag = t2*2 + part (part 0=hi, 1=lo).
// h = (2*wave + t2)*16 + (lane&15); k = c*32 + (lane>>4)*8 + j; zero-pad k >= 300.
__global__ void wsplit_kernel(const float* __restrict__ W, u16* __restrict__ Wfrag)
{
    int i = blockIdx.x * 256 + threadIdx.x;
    if (i >= WFRAG_ELEMS) return;
    int j    = i & 7;
    int lane = (i >> 3) & 63;
    int frag = (i >> 9) & 3;
    int wave = (i >> 11) & 3;
    int c    = i >> 13;
    int nn = lane & 15, quad = lane >> 4;
    int t2 = frag >> 1, part = frag & 1;
    int h = (2 * wave + t2) * 16 + nn;
    int k = c * 32 + quad * 8 + j;
    float w = (k < K_FEAT) ? W[(size_t)k * H + h] : 0.f;
    u16 hi = f2bf(w);
    Wfrag[i] = part ? f2bf(w - bf2f(hi)) : hi;
}

// ---------------- Fused kernel: FC+ReLU MFMA + barrier + mean + softmax + outputs ---------
__global__ __launch_bounds__(256, 3) void fused_kernel(
    const float* __restrict__ seq_a, const float* __restrict__ seq_b,
    const u16* __restrict__ Wfrag, const float* __restrict__ bias,
    const int* __restrict__ mask_a, const int* __restrict__ mask_b,
    float* __restrict__ psum_a, float* __restrict__ psum_b,
    u32* __restrict__ bar,
    float* __restrict__ out)
{
    __shared__ u16 Ah_s[TM * LDA];      // 10240 B
    __shared__ u16 Al_s[TM * LDA];      // 10240 B
    __shared__ float bias_s[H];
    __shared__ float mean_s[H];
    __shared__ float score_part[128 * 4];
    __shared__ float w_s[128];
    __shared__ float red[4];

    int n = blockIdx.x;
    int side = (n >= NREV) ? 1 : 0;
    int r = n - side * NREV;            // review index within side
    int sample = r / 10;
    const float* seq = side ? seq_b : seq_a;
    const int* mask = side ? mask_b : mask_a;
    float* psum = side ? psum_b : psum_a;

    const int tid = threadIdx.x;
    const int tok0 = r * TM;
    const int wave = tid >> 6;
    const int lane = tid & 63;
    const int nn = lane & 15;
    const int quad = lane >> 4;

    if (tid < H) bias_s[tid] = bias[tid];

    const int st_t = tid >> 3;
    const int st_j = tid & 7;

    f32x4 acc[8][2];                    // [tt][ht]
#pragma unroll
    for (int m = 0; m < 8; ++m) {
        acc[m][0] = (f32x4){0.f, 0.f, 0.f, 0.f};
        acc[m][1] = (f32x4){0.f, 0.f, 0.f, 0.f};
    }

    float4 pf[4];
    // prologue: load + convert + store chunk 0
#pragma unroll
    for (int it = 0; it < 4; ++it) {
        int t = st_t + it * 32;
        int kk = 4 * st_j;
        pf[it] = make_float4(0.f, 0.f, 0.f, 0.f);
        if (kk + 4 <= K_FEAT)
            pf[it] = *(const float4*)&seq[(size_t)(tok0 + t) * K_FEAT + kk];
    }
#pragma unroll
    for (int it = 0; it < 4; ++it) {
        int t = st_t + it * 32;
        float4 v = pf[it];
        u16 h0 = f2bf(v.x), h1 = f2bf(v.y), h2 = f2bf(v.z), h3 = f2bf(v.w);
        uint2 hp, lp;
        hp.x = (u32)h0 | ((u32)h1 << 16);
        hp.y = (u32)h2 | ((u32)h3 << 16);
        lp.x = (u32)f2bf(v.x - bf2f(h0)) | ((u32)f2bf(v.y - bf2f(h1)) << 16);
        lp.y = (u32)f2bf(v.z - bf2f(h2)) | ((u32)f2bf(v.w - bf2f(h3)) << 16);
        *(uint2*)&Ah_s[t * LDA + 4 * st_j] = hp;
        *(uint2*)&Al_s[t * LDA + 4 * st_j] = lp;
    }
    __syncthreads();

    for (int c = 0; c < NCHUNK; ++c) {
        if (c < NCHUNK - 1) {
#pragma unroll
            for (int it = 0; it < 4; ++it) {
                int t = st_t + it * 32;
                int kk = (c + 1) * 32 + 4 * st_j;
                pf[it] = make_float4(0.f, 0.f, 0.f, 0.f);
                if (kk + 4 <= K_FEAT)
                    pf[it] = *(const float4*)&seq[(size_t)(tok0 + t) * K_FEAT + kk];
            }
        }
        const u16* wf = Wfrag + (size_t)(c * 4 + wave) * 2048;
        bf16x8 bh0 = *(const bf16x8*)&wf[0 * 512 + lane * 8];
        bf16x8 bl0 = *(const bf16x8*)&wf[1 * 512 + lane * 8];
        bf16x8 bh1 = *(const bf16x8*)&wf[2 * 512 + lane * 8];
        bf16x8 bl1 = *(const bf16x8*)&wf[3 * 512 + lane * 8];
#pragma unroll
        for (int m = 0; m < 8; ++m) {
            bf16x8 a_hi = *(const bf16x8*)&Ah_s[(m * 16 + nn) * LDA + quad * 8];
            bf16x8 a_lo = *(const bf16x8*)&Al_s[(m * 16 + nn) * LDA + quad * 8];
            // swapped operands: D[h][tok]
            acc[m][0] = __builtin_amdgcn_mfma_f32_16x16x32_bf16(bh0, a_hi, acc[m][0], 0, 0, 0);
            acc[m][0] = __builtin_amdgcn_mfma_f32_16x16x32_bf16(bl0, a_hi, acc[m][0], 0, 0, 0);
            acc[m][0] = __builtin_amdgcn_mfma_f32_16x16x32_bf16(bh0, a_lo, acc[m][0], 0, 0, 0);
            acc[m][1] = __builtin_amdgcn_mfma_f32_16x16x32_bf16(bh1, a_hi, acc[m][1], 0, 0, 0);
            acc[m][1] = __builtin_amdgcn_mfma_f32_16x16x32_bf16(bl1, a_hi, acc[m][1], 0, 0, 0);
            acc[m][1] = __builtin_amdgcn_mfma_f32_16x16x32_bf16(bh1, a_lo, acc[m][1], 0, 0, 0);
        }
        __syncthreads();
        if (c < NCHUNK - 1) {
#pragma unroll
            for (int it = 0; it < 4; ++it) {
                int t = st_t + it * 32;
                float4 v = pf[it];
                u16 h0 = f2bf(v.x), h1 = f2bf(v.y), h2 = f2bf(v.z), h3 = f2bf(v.w);
                uint2 hp, lp;
                hp.x = (u32)h0 | ((u32)h1 << 16);
                hp.y = (u32)h2 | ((u32)h3 << 16);
                lp.x = (u32)f2bf(v.x - bf2f(h0)) | ((u32)f2bf(v.y - bf2f(h1)) << 16);
                lp.y = (u32)f2bf(v.z - bf2f(h2)) | ((u32)f2bf(v.w - bf2f(h3)) << 16);
                *(uint2*)&Ah_s[t * LDA + 4 * st_j] = hp;
                *(uint2*)&Al_s[t * LDA + 4 * st_j] = lp;
            }
            __syncthreads();
        }
    }

    // ---- finalize t = relu(acc + bias) in registers ----
    float4 bb0 = *(const float4*)&bias_s[(2 * wave + 0) * 16 + quad * 4];
    float4 bb1 = *(const float4*)&bias_s[(2 * wave + 1) * 16 + quad * 4];
#pragma unroll
    for (int tt = 0; tt < 8; ++tt) {
        acc[tt][0][0] = fmaxf(acc[tt][0][0] + bb0.x, 0.f);
        acc[tt][0][1] = fmaxf(acc[tt][0][1] + bb0.y, 0.f);
        acc[tt][0][2] = fmaxf(acc[tt][0][2] + bb0.z, 0.f);
        acc[tt][0][3] = fmaxf(acc[tt][0][3] + bb0.w, 0.f);
        acc[tt][1][0] = fmaxf(acc[tt][1][0] + bb1.x, 0.f);
        acc[tt][1][1] = fmaxf(acc[tt][1][1] + bb1.y, 0.f);
        acc[tt][1][2] = fmaxf(acc[tt][1][2] + bb1.z, 0.f);
        acc[tt][1][3] = fmaxf(acc[tt][1][3] + bb1.w, 0.f);
    }

    // ---- psum: per-review feature sums, published with agent-scope atomic stores ----
#pragma unroll
    for (int ht = 0; ht < 2; ++ht) {
        int h0 = (2 * wave + ht) * 16 + quad * 4;
        float fs[4] = {0.f, 0.f, 0.f, 0.f};
#pragma unroll
        for (int tt = 0; tt < 8; ++tt) {
            fs[0] += acc[tt][ht][0];
            fs[1] += acc[tt][ht][1];
            fs[2] += acc[tt][ht][2];
            fs[3] += acc[tt][ht][3];
        }
#pragma unroll
        for (int g = 0; g < 4; ++g) {
            fs[g] += __shfl_xor(fs[g], 1);
            fs[g] += __shfl_xor(fs[g], 2);
            fs[g] += __shfl_xor(fs[g], 4);
            fs[g] += __shfl_xor(fs[g], 8);
        }
        if (nn == 0) {
#pragma unroll
            for (int g = 0; g < 4; ++g)
                __hip_atomic_store(&psum[(size_t)r * H + h0 + g], fs[g],
                                   __ATOMIC_RELAXED, __HIP_MEMORY_SCOPE_AGENT);
        }
    }

    // ---- software grid barrier (all 640 blocks co-resident by construction) ----
    __syncthreads();   // drains vmcnt: all psum stores device-visible before arrival
    if (tid == 0) {
        __hip_atomic_fetch_add(bar, 1u, __ATOMIC_RELEASE, __HIP_MEMORY_SCOPE_AGENT);
        while (__hip_atomic_load(bar, __ATOMIC_ACQUIRE, __HIP_MEMORY_SCOPE_AGENT) < (u32)NBLOCKS)
            __builtin_amdgcn_s_sleep(8);
    }
    __syncthreads();

    // ---- mean of the OTHER side's sample (agent-scope atomic loads, cross-XCD safe) ----
    const float* psum_o = side ? psum_a : psum_b;
    if (tid < H) {
        float s = 0.f;
#pragma unroll
        for (int i = 0; i < 10; ++i)
            s += __hip_atomic_load(&psum_o[(size_t)sample * 10 * H + (size_t)i * H + tid],
                                   __ATOMIC_RELAXED, __HIP_MEMORY_SCOPE_AGENT);
        mean_s[tid] = s * (1.0f / (float)TOK_PER_SAMPLE);
    }
    __syncthreads();

    // ---- scores from registers: score[tok] = dot(t[tok][:], mean) ----
    float4 mm0 = *(const float4*)&mean_s[(2 * wave + 0) * 16 + quad * 4];
    float4 mm1 = *(const float4*)&mean_s[(2 * wave + 1) * 16 + quad * 4];
#pragma unroll
    for (int tt = 0; tt < 8; ++tt) {
        float sp = acc[tt][0][0] * mm0.x + acc[tt][0][1] * mm0.y
                 + acc[tt][0][2] * mm0.z + acc[tt][0][3] * mm0.w
                 + acc[tt][1][0] * mm1.x + acc[tt][1][1] * mm1.y
                 + acc[tt][1][2] * mm1.z + acc[tt][1][3] * mm1.w;
        sp += __shfl_xor(sp, 16);
        sp += __shfl_xor(sp, 32);
        if (quad == 0) score_part[(tt * 16 + nn) * 4 + wave] = sp;
    }
    __syncthreads();

    // ---- masked softmax over 128 tokens ----
    float logit = -1e9f;
    if (tid < 128) {
        float s = score_part[tid * 4 + 0] + score_part[tid * 4 + 1]
                + score_part[tid * 4 + 2] + score_part[tid * 4 + 3];
        int mv = mask[r * 128 + tid];
        logit = (mv > 0) ? s : -1e9f;
    }
    float mx = logit;
    for (int off = 32; off > 0; off >>= 1) mx = fmaxf(mx, __shfl_xor(mx, off));
    if ((tid & 63) == 0) red[tid >> 6] = mx;
    __syncthreads();
    mx = fmaxf(fmaxf(red[0], red[1]), fmaxf(red[2], red[3]));
    __syncthreads();

    float e = __expf(logit - mx);
    float ssum = e;
    for (int off = 32; off > 0; off >>= 1) ssum += __shfl_xor(ssum, off);
    if ((tid & 63) == 0) red[tid >> 6] = ssum;
    __syncthreads();
    ssum = red[0] + red[1] + red[2] + red[3];

    float* out_w = out + 2 * NREV * H + (size_t)side * NREV * H;
    float wgt = e / ssum;
    if (tid < 128) {
        w_s[tid] = wgt;
        out_w[(size_t)r * 128 + tid] = wgt;
    }
    __syncthreads();

    // ---- weighted sum from registers: out[h] = sum_tok w[tok] * t[tok][h] ----
    float* out_vec = out + (size_t)side * NREV * H;
#pragma unroll
    for (int ht = 0; ht < 2; ++ht) {
        int h0 = (2 * wave + ht) * 16 + quad * 4;
        float po[4] = {0.f, 0.f, 0.f, 0.f};
#pragma unroll
        for (int tt = 0; tt < 8; ++tt) {
            float wl = w_s[tt * 16 + nn];
            po[0] = fmaf(wl, acc[tt][ht][0], po[0]);
            po[1] = fmaf(wl, acc[tt][ht][1], po[1]);
            po[2] = fmaf(wl, acc[tt][ht][2], po[2]);
            po[3] = fmaf(wl, acc[tt][ht][3], po[3]);
        }
#pragma unroll
        for (int g = 0; g < 4; ++g) {
            po[g] += __shfl_xor(po[g], 1);
            po[g] += __shfl_xor(po[g], 2);
            po[g] += __shfl_xor(po[g], 4);
            po[g] += __shfl_xor(po[g], 8);
        }
        if (nn == 0) {
#pragma unroll
            for (int g = 0; g < 4; ++g)
                out_vec[(size_t)r * H + h0 + g] = po[g];
        }
    }
}

// ---------------- Launch ----------------
extern "C" void kernel_launch(void* const* d_in, const int* in_sizes, int n_in,
                              void* d_out, int out_size, void* d_ws, size_t ws_size,
                              hipStream_t stream)
{
    const float* seq_a = (const float*)d_in[0];
    const float* seq_b = (const float*)d_in[1];
    const int* mask_a = (const int*)d_in[2];
    const int* mask_b = (const int*)d_in[3];
    const float* W = (const float*)d_in[4];
    const float* bias = (const float*)d_in[5];
    float* out = (float*)d_out;

    float* psum_a = (float*)d_ws;                     // 320*128 f32
    float* psum_b = psum_a + NREV * H;                // 320*128 f32
    u16* Wfrag = (u16*)(psum_b + NREV * H);           // 81920 bf16
    u32* bar = (u32*)(Wfrag + WFRAG_ELEMS);           // 1 u32 barrier counter

    bar_init_kernel<<<1, 64, 0, stream>>>(bar);
    wsplit_kernel<<<(WFRAG_ELEMS + 255) / 256, 256, 0, stream>>>(W, Wfrag);
    fused_kernel<<<NBLOCKS, 256, 0, stream>>>(seq_a, seq_b, Wfrag, bias,
                                              mask_a, mask_b, psum_a, psum_b, bar, out);
}

// Round 11
// 194.242 us; speedup vs baseline: 1.1988x; 1.1988x over previous
//
#include <hip/hip_runtime.h>
#include <hip/hip_bf16.h>

// Shapes: bz=32, rv_num=10, rv_len=128, in_feat=300, out_feat=128
// N = 320 reviews/side, tokens/side = 40960, M = 1280 tokens/sample.
// Fused design: block n == review n (side = n/320). After the fc K-loop the
// block holds its review's 128x128 fp32 tile in registers; only the other
// side's sample-mean crosses blocks. Sync: per-(side,sample) counters --
// producers release-add after publishing psum; consumers spin RELAXED (no
// cache-invalidate storm) on the partner counter, one-shot ACQUIRE on exit.
// Co-residency: 24.6 KB LDS + launch_bounds(256,3) => >=3 blocks/CU => 768 >= 640.

#define K_FEAT 300
#define H 128
#define NREV 320
#define TOK_PER_SAMPLE 1280
#define TM 128
#define LDA 40                      // LDS row stride in bf16 (32 k + 8 pad)
#define NCHUNK 10
#define WFRAG_ELEMS (NCHUNK * 4 * 4 * 64 * 8)   // 81920 bf16 = 160 KB
#define NBLOCKS (2 * NREV)          // 640
#define NSAMP 32

typedef __attribute__((ext_vector_type(8))) short bf16x8;
typedef __attribute__((ext_vector_type(4))) float f32x4;
typedef unsigned short u16;
typedef unsigned int u32;

static __device__ __forceinline__ u16 f2bf(float x) {
    u32 u = __float_as_uint(x);
    return (u16)((u + 0x7fffu + ((u >> 16) & 1u)) >> 16);
}
static __device__ __forceinline__ float bf2f(u16 s) {
    return __uint_as_float(((u32)s) << 16);
}

// ---------------- Kernel 0a: zero the 64 sample counters ----------------
__global__ void bar_init_kernel(u32* __restrict__ cnt)
{
    if (threadIdx.x < 2 * NSAMP) cnt[threadIdx.x] = 0u;
}

// ---------------- Kernel 0b: pack W into per-(chunk,wave,frag,lane) bf16 fragments --------
// Wfrag[c][wave][frag][lane][8]; frag = t2*2 + part (part 0=hi, 1=lo).
// h = (2*wave + t2)*16 + (lane&15); k = c*32 + (lane>>4)*8 + j; zero-pad k >= 300.
__global__ void wsplit_kernel(const float* __restrict__ W, u16* __restrict__ Wfrag)
{
    int i = blockIdx.x * 256 + threadIdx.x;
    if (i >= WFRAG_ELEMS) return;
    int j    = i & 7;
    int lane = (i >> 3) & 63;
    int frag = (i >> 9) & 3;
    int wave = (i >> 11) & 3;
    int c    = i >> 13;
    int nn = lane & 15, quad = lane >> 4;
    int t2 = frag >> 1, part = frag & 1;
    int h = (2 * wave + t2) * 16 + nn;
    int k = c * 32 + quad * 8 + j;
    float w = (k < K_FEAT) ? W[(size_t)k * H + h] : 0.f;
    u16 hi = f2bf(w);
    Wfrag[i] = part ? f2bf(w - bf2f(hi)) : hi;
}

// ---------------- Fused kernel: FC+ReLU MFMA + sample-sync + mean + softmax + outputs -----
__global__ __launch_bounds__(256, 3) void fused_kernel(
    const float* __restrict__ seq_a, const float* __restrict__ seq_b,
    const u16* __restrict__ Wfrag, const float* __restrict__ bias,
    const int* __restrict__ mask_a, const int* __restrict__ mask_b,
    float* __restrict__ psum_a, float* __restrict__ psum_b,
    u32* __restrict__ cnt,
    float* __restrict__ out)
{
    __shared__ u16 Ah_s[TM * LDA];      // 10240 B
    __shared__ u16 Al_s[TM * LDA];      // 10240 B
    __shared__ float bias_s[H];
    __shared__ float mean_s[H];
    __shared__ float score_part[128 * 4];
    __shared__ float w_s[128];
    __shared__ float red[4];

    int n = blockIdx.x;
    int side = (n >= NREV) ? 1 : 0;
    int r = n - side * NREV;            // review index within side
    int sample = r / 10;
    const float* seq = side ? seq_b : seq_a;
    const int* mask = side ? mask_b : mask_a;
    float* psum = side ? psum_b : psum_a;

    const int tid = threadIdx.x;
    const int tok0 = r * TM;
    const int wave = tid >> 6;
    const int lane = tid & 63;
    const int nn = lane & 15;
    const int quad = lane >> 4;

    if (tid < H) bias_s[tid] = bias[tid];

    const int st_t = tid >> 3;
    const int st_j = tid & 7;

    f32x4 acc[8][2];                    // [tt][ht]
#pragma unroll
    for (int m = 0; m < 8; ++m) {
        acc[m][0] = (f32x4){0.f, 0.f, 0.f, 0.f};
        acc[m][1] = (f32x4){0.f, 0.f, 0.f, 0.f};
    }

    float4 pf[4];
    // prologue: load + convert + store chunk 0
#pragma unroll
    for (int it = 0; it < 4; ++it) {
        int t = st_t + it * 32;
        int kk = 4 * st_j;
        pf[it] = make_float4(0.f, 0.f, 0.f, 0.f);
        if (kk + 4 <= K_FEAT)
            pf[it] = *(const float4*)&seq[(size_t)(tok0 + t) * K_FEAT + kk];
    }
#pragma unroll
    for (int it = 0; it < 4; ++it) {
        int t = st_t + it * 32;
        float4 v = pf[it];
        u16 h0 = f2bf(v.x), h1 = f2bf(v.y), h2 = f2bf(v.z), h3 = f2bf(v.w);
        uint2 hp, lp;
        hp.x = (u32)h0 | ((u32)h1 << 16);
        hp.y = (u32)h2 | ((u32)h3 << 16);
        lp.x = (u32)f2bf(v.x - bf2f(h0)) | ((u32)f2bf(v.y - bf2f(h1)) << 16);
        lp.y = (u32)f2bf(v.z - bf2f(h2)) | ((u32)f2bf(v.w - bf2f(h3)) << 16);
        *(uint2*)&Ah_s[t * LDA + 4 * st_j] = hp;
        *(uint2*)&Al_s[t * LDA + 4 * st_j] = lp;
    }
    __syncthreads();

    for (int c = 0; c < NCHUNK; ++c) {
        if (c < NCHUNK - 1) {
#pragma unroll
            for (int it = 0; it < 4; ++it) {
                int t = st_t + it * 32;
                int kk = (c + 1) * 32 + 4 * st_j;
                pf[it] = make_float4(0.f, 0.f, 0.f, 0.f);
                if (kk + 4 <= K_FEAT)
                    pf[it] = *(const float4*)&seq[(size_t)(tok0 + t) * K_FEAT + kk];
            }
        }
        const u16* wf = Wfrag + (size_t)(c * 4 + wave) * 2048;
        bf16x8 bh0 = *(const bf16x8*)&wf[0 * 512 + lane * 8];
        bf16x8 bl0 = *(const bf16x8*)&wf[1 * 512 + lane * 8];
        bf16x8 bh1 = *(const bf16x8*)&wf[2 * 512 + lane * 8];
        bf16x8 bl1 = *(const bf16x8*)&wf[3 * 512 + lane * 8];
#pragma unroll
        for (int m = 0; m < 8; ++m) {
            bf16x8 a_hi = *(const bf16x8*)&Ah_s[(m * 16 + nn) * LDA + quad * 8];
            bf16x8 a_lo = *(const bf16x8*)&Al_s[(m * 16 + nn) * LDA + quad * 8];
            // swapped operands: D[h][tok]
            acc[m][0] = __builtin_amdgcn_mfma_f32_16x16x32_bf16(bh0, a_hi, acc[m][0], 0, 0, 0);
            acc[m][0] = __builtin_amdgcn_mfma_f32_16x16x32_bf16(bl0, a_hi, acc[m][0], 0, 0, 0);
            acc[m][0] = __builtin_amdgcn_mfma_f32_16x16x32_bf16(bh0, a_lo, acc[m][0], 0, 0, 0);
            acc[m][1] = __builtin_amdgcn_mfma_f32_16x16x32_bf16(bh1, a_hi, acc[m][1], 0, 0, 0);
            acc[m][1] = __builtin_amdgcn_mfma_f32_16x16x32_bf16(bl1, a_hi, acc[m][1], 0, 0, 0);
            acc[m][1] = __builtin_amdgcn_mfma_f32_16x16x32_bf16(bh1, a_lo, acc[m][1], 0, 0, 0);
        }
        __syncthreads();
        if (c < NCHUNK - 1) {
#pragma unroll
            for (int it = 0; it < 4; ++it) {
                int t = st_t + it * 32;
                float4 v = pf[it];
                u16 h0 = f2bf(v.x), h1 = f2bf(v.y), h2 = f2bf(v.z), h3 = f2bf(v.w);
                uint2 hp, lp;
                hp.x = (u32)h0 | ((u32)h1 << 16);
                hp.y = (u32)h2 | ((u32)h3 << 16);
                lp.x = (u32)f2bf(v.x - bf2f(h0)) | ((u32)f2bf(v.y - bf2f(h1)) << 16);
                lp.y = (u32)f2bf(v.z - bf2f(h2)) | ((u32)f2bf(v.w - bf2f(h3)) << 16);
                *(uint2*)&Ah_s[t * LDA + 4 * st_j] = hp;
                *(uint2*)&Al_s[t * LDA + 4 * st_j] = lp;
            }
            __syncthreads();
        }
    }

    // ---- finalize t = relu(acc + bias) in registers ----
    float4 bb0 = *(const float4*)&bias_s[(2 * wave + 0) * 16 + quad * 4];
    float4 bb1 = *(const float4*)&bias_s[(2 * wave + 1) * 16 + quad * 4];
#pragma unroll
    for (int tt = 0; tt < 8; ++tt) {
        acc[tt][0][0] = fmaxf(acc[tt][0][0] + bb0.x, 0.f);
        acc[tt][0][1] = fmaxf(acc[tt][0][1] + bb0.y, 0.f);
        acc[tt][0][2] = fmaxf(acc[tt][0][2] + bb0.z, 0.f);
        acc[tt][0][3] = fmaxf(acc[tt][0][3] + bb0.w, 0.f);
        acc[tt][1][0] = fmaxf(acc[tt][1][0] + bb1.x, 0.f);
        acc[tt][1][1] = fmaxf(acc[tt][1][1] + bb1.y, 0.f);
        acc[tt][1][2] = fmaxf(acc[tt][1][2] + bb1.z, 0.f);
        acc[tt][1][3] = fmaxf(acc[tt][1][3] + bb1.w, 0.f);
    }

    // ---- psum: per-review feature sums, published with agent-scope atomic stores ----
#pragma unroll
    for (int ht = 0; ht < 2; ++ht) {
        int h0 = (2 * wave + ht) * 16 + quad * 4;
        float fs[4] = {0.f, 0.f, 0.f, 0.f};
#pragma unroll
        for (int tt = 0; tt < 8; ++tt) {
            fs[0] += acc[tt][ht][0];
            fs[1] += acc[tt][ht][1];
            fs[2] += acc[tt][ht][2];
            fs[3] += acc[tt][ht][3];
        }
#pragma unroll
        for (int g = 0; g < 4; ++g) {
            fs[g] += __shfl_xor(fs[g], 1);
            fs[g] += __shfl_xor(fs[g], 2);
            fs[g] += __shfl_xor(fs[g], 4);
            fs[g] += __shfl_xor(fs[g], 8);
        }
        if (nn == 0) {
#pragma unroll
            for (int g = 0; g < 4; ++g)
                __hip_atomic_store(&psum[(size_t)r * H + h0 + g], fs[g],
                                   __ATOMIC_RELAXED, __HIP_MEMORY_SCOPE_AGENT);
        }
    }

    // ---- sample-scoped sync: publish mine, wait for partner sample's 10 blocks ----
    __syncthreads();   // all psum stores issued before the release-add
    if (tid == 0) {
        // release: orders this block's psum stores before the counter bump
        __hip_atomic_fetch_add(&cnt[side * NSAMP + sample], 1u,
                               __ATOMIC_RELEASE, __HIP_MEMORY_SCOPE_AGENT);
        // spin RELAXED (no per-poll cache invalidate), s_sleep backoff
        const u32* pc = &cnt[(1 - side) * NSAMP + sample];
        while (__hip_atomic_load(pc, __ATOMIC_RELAXED, __HIP_MEMORY_SCOPE_AGENT) < 10u)
            __builtin_amdgcn_s_sleep(16);
        // one-shot acquire to pair with producers' releases
        (void)__hip_atomic_load(pc, __ATOMIC_ACQUIRE, __HIP_MEMORY_SCOPE_AGENT);
    }
    __syncthreads();

    // ---- mean of the OTHER side's sample (agent-scope loads bypass stale L1) ----
    const float* psum_o = side ? psum_a : psum_b;
    if (tid < H) {
        float s = 0.f;
#pragma unroll
        for (int i = 0; i < 10; ++i)
            s += __hip_atomic_load(&psum_o[(size_t)sample * 10 * H + (size_t)i * H + tid],
                                   __ATOMIC_RELAXED, __HIP_MEMORY_SCOPE_AGENT);
        mean_s[tid] = s * (1.0f / (float)TOK_PER_SAMPLE);
    }
    __syncthreads();

    // ---- scores from registers: score[tok] = dot(t[tok][:], mean) ----
    float4 mm0 = *(const float4*)&mean_s[(2 * wave + 0) * 16 + quad * 4];
    float4 mm1 = *(const float4*)&mean_s[(2 * wave + 1) * 16 + quad * 4];
#pragma unroll
    for (int tt = 0; tt < 8; ++tt) {
        float sp = acc[tt][0][0] * mm0.x + acc[tt][0][1] * mm0.y
                 + acc[tt][0][2] * mm0.z + acc[tt][0][3] * mm0.w
                 + acc[tt][1][0] * mm1.x + acc[tt][1][1] * mm1.y
                 + acc[tt][1][2] * mm1.z + acc[tt][1][3] * mm1.w;
        sp += __shfl_xor(sp, 16);
        sp += __shfl_xor(sp, 32);
        if (quad == 0) score_part[(tt * 16 + nn) * 4 + wave] = sp;
    }
    __syncthreads();

    // ---- masked softmax over 128 tokens ----
    float logit = -1e9f;
    if (tid < 128) {
        float s = score_part[tid * 4 + 0] + score_part[tid * 4 + 1]
                + score_part[tid * 4 + 2] + score_part[tid * 4 + 3];
        int mv = mask[r * 128 + tid];
        logit = (mv > 0) ? s : -1e9f;
    }
    float mx = logit;
    for (int off = 32; off > 0; off >>= 1) mx = fmaxf(mx, __shfl_xor(mx, off));
    if ((tid & 63) == 0) red[tid >> 6] = mx;
    __syncthreads();
    mx = fmaxf(fmaxf(red[0], red[1]), fmaxf(red[2], red[3]));
    __syncthreads();

    float e = __expf(logit - mx);
    float ssum = e;
    for (int off = 32; off > 0; off >>= 1) ssum += __shfl_xor(ssum, off);
    if ((tid & 63) == 0) red[tid >> 6] = ssum;
    __syncthreads();
    ssum = red[0] + red[1] + red[2] + red[3];

    float* out_w = out + 2 * NREV * H + (size_t)side * NREV * H;
    float wgt = e / ssum;
    if (tid < 128) {
        w_s[tid] = wgt;
        out_w[(size_t)r * 128 + tid] = wgt;
    }
    __syncthreads();

    // ---- weighted sum from registers: out[h] = sum_tok w[tok] * t[tok][h] ----
    float* out_vec = out + (size_t)side * NREV * H;
#pragma unroll
    for (int ht = 0; ht < 2; ++ht) {
        int h0 = (2 * wave + ht) * 16 + quad * 4;
        float po[4] = {0.f, 0.f, 0.f, 0.f};
#pragma unroll
        for (int tt = 0; tt < 8; ++tt) {
            float wl = w_s[tt * 16 + nn];
            po[0] = fmaf(wl, acc[tt][ht][0], po[0]);
            po[1] = fmaf(wl, acc[tt][ht][1], po[1]);
            po[2] = fmaf(wl, acc[tt][ht][2], po[2]);
            po[3] = fmaf(wl, acc[tt][ht][3], po[3]);
        }
#pragma unroll
        for (int g = 0; g < 4; ++g) {
            po[g] += __shfl_xor(po[g], 1);
            po[g] += __shfl_xor(po[g], 2);
            po[g] += __shfl_xor(po[g], 4);
            po[g] += __shfl_xor(po[g], 8);
        }
        if (nn == 0) {
#pragma unroll
            for (int g = 0; g < 4; ++g)
                out_vec[(size_t)r * H + h0 + g] = po[g];
        }
    }
}

// ---------------- Launch ----------------
extern "C" void kernel_launch(void* const* d_in, const int* in_sizes, int n_in,
                              void* d_out, int out_size, void* d_ws, size_t ws_size,
                              hipStream_t stream)
{
    const float* seq_a = (const float*)d_in[0];
    const float* seq_b = (const float*)d_in[1];
    const int* mask_a = (const int*)d_in[2];
    const int* mask_b = (const int*)d_in[3];
    const float* W = (const float*)d_in[4];
    const float* bias = (const float*)d_in[5];
    float* out = (float*)d_out;

    float* psum_a = (float*)d_ws;                     // 320*128 f32
    float* psum_b = psum_a + NREV * H;                // 320*128 f32
    u16* Wfrag = (u16*)(psum_b + NREV * H);           // 81920 bf16
    u32* cnt = (u32*)(Wfrag + WFRAG_ELEMS);           // 64 sample counters

    bar_init_kernel<<<1, 64, 0, stream>>>(cnt);
    wsplit_kernel<<<(WFRAG_ELEMS + 255) / 256, 256, 0, stream>>>(W, Wfrag);
    fused_kernel<<<NBLOCKS, 256, 0, stream>>>(seq_a, seq_b, Wfrag, bias,
                                              mask_a, mask_b, psum_a, psum_b, cnt, out);
}

// Round 12
// 173.793 us; speedup vs baseline: 1.3398x; 1.1177x over previous
//
#include <hip/hip_runtime.h>
#include <hip/hip_bf16.h>

// Shapes: bz=32, rv_num=10, rv_len=128, in_feat=300, out_feat=128
// N = 320 reviews/side, tokens/side = 40960, M = 1280 tokens/sample.
// R12: two-kernel structure (R8-proven) with a barrier-free fc K-loop.
// fc: wave = 2 m-tiles (32 tokens) x all 128 features. A-fragments gathered
// straight from global into registers (lane map nn=token, quad*8+j=k, proven
// in R8's swapped-operand MFMA); W pre-fragmented (L2-hot), double-buffered
// across the n-loop. No LDS staging, no K-loop barriers -> waves fully async.

#define K_FEAT 300
#define H 128
#define NTOK 40960
#define NREV 320
#define TOK_PER_SAMPLE 1280
#define BLKS_PER_SAMPLE 10
#define NCHUNK 10
#define WFRAG_ELEMS (NCHUNK * 8 * 2 * 64 * 8)   // 81920 bf16 = 160 KB

typedef __attribute__((ext_vector_type(8))) short bf16x8;
typedef __attribute__((ext_vector_type(4))) float f32x4;
typedef unsigned short u16;
typedef unsigned int u32;

static __device__ __forceinline__ u16 f2bf(float x) {
    u32 u = __float_as_uint(x);
    return (u16)((u + 0x7fffu + ((u >> 16) & 1u)) >> 16);
}
static __device__ __forceinline__ float bf2f(u16 s) {
    return __uint_as_float(((u32)s) << 16);
}

union bfpack { uint4 u; bf16x8 v; };

// ---------------- Kernel 0: pack W into per-(chunk,n-tile,part,lane) bf16 fragments -------
// Wfrag[c][n][part][lane][8]; part 0=hi, 1=lo. h = n*16 + (lane&15);
// k = c*32 + (lane>>4)*8 + j; zero-pad k >= 300.
__global__ void wsplit_kernel(const float* __restrict__ W, u16* __restrict__ Wfrag)
{
    int i = blockIdx.x * 256 + threadIdx.x;
    if (i >= WFRAG_ELEMS) return;
    int j    = i & 7;
    int lane = (i >> 3) & 63;
    int part = (i >> 9) & 1;
    int n    = (i >> 10) & 7;
    int c    = i >> 13;
    int h = n * 16 + (lane & 15);
    int k = c * 32 + (lane >> 4) * 8 + j;
    float w = (k < K_FEAT) ? W[(size_t)k * H + h] : 0.f;
    u16 hi = f2bf(w);
    Wfrag[i] = part ? f2bf(w - bf2f(hi)) : hi;
}

// ---------------- Kernel 1: FC + ReLU, barrier-free 3-term split-bf16 MFMA ----------------
// grid.x = 640 (320/side); block = 256 (4 waves). Tile 128 tok x 128 feat.
__global__ __launch_bounds__(256, 3) void fc_mfma_kernel(
    const float* __restrict__ seq_a, const float* __restrict__ seq_b,
    const u16* __restrict__ Wfrag, const float* __restrict__ bias,
    u16* __restrict__ ta, u16* __restrict__ tb,
    float* __restrict__ psum_a, float* __restrict__ psum_b)
{
    __shared__ float psum_s[4][H];
    __shared__ float bias_s[H];

    int blk = blockIdx.x;
    const float* seq; u16* outp; float* psum;
    if (blk < 320) { seq = seq_a; outp = ta; psum = psum_a; }
    else           { seq = seq_b; outp = tb; psum = psum_b; blk -= 320; }

    const int tid = threadIdx.x;
    const int tok0 = blk * 128;
    const int wave = tid >> 6;
    const int lane = tid & 63;
    const int nn = lane & 15;
    const int quad = lane >> 4;

    if (tid < H) bias_s[tid] = bias[tid];

    // lane's two token rows (mi = 0,1)
    const float* row0 = seq + (size_t)(tok0 + wave * 32 + nn) * K_FEAT;
    const float* row1 = row0 + (size_t)16 * K_FEAT;

    f32x4 acc[2][8];                    // [mi][n-tile]
#pragma unroll
    for (int mi = 0; mi < 2; ++mi)
#pragma unroll
        for (int n = 0; n < 8; ++n) acc[mi][n] = (f32x4){0.f, 0.f, 0.f, 0.f};

    // prologue: chunk 0 A loads (k <= 35 < 300, unconditional)
    float4 pf[2][2];
    {
        int kk = quad * 8;
        pf[0][0] = *(const float4*)&row0[kk];
        pf[0][1] = *(const float4*)&row0[kk + 4];
        pf[1][0] = *(const float4*)&row1[kk];
        pf[1][1] = *(const float4*)&row1[kk + 4];
    }

    for (int c = 0; c < NCHUNK; ++c) {
        // convert current chunk's A to hi/lo fragments (registers only)
        bf16x8 ah[2], al[2];
#pragma unroll
        for (int mi = 0; mi < 2; ++mi) {
            float v[8] = {pf[mi][0].x, pf[mi][0].y, pf[mi][0].z, pf[mi][0].w,
                          pf[mi][1].x, pf[mi][1].y, pf[mi][1].z, pf[mi][1].w};
            u16 hh[8];
            bfpack ph, pl;
#pragma unroll
            for (int j = 0; j < 8; ++j) hh[j] = f2bf(v[j]);
            ph.u.x = (u32)hh[0] | ((u32)hh[1] << 16);
            ph.u.y = (u32)hh[2] | ((u32)hh[3] << 16);
            ph.u.z = (u32)hh[4] | ((u32)hh[5] << 16);
            ph.u.w = (u32)hh[6] | ((u32)hh[7] << 16);
            pl.u.x = (u32)f2bf(v[0] - bf2f(hh[0])) | ((u32)f2bf(v[1] - bf2f(hh[1])) << 16);
            pl.u.y = (u32)f2bf(v[2] - bf2f(hh[2])) | ((u32)f2bf(v[3] - bf2f(hh[3])) << 16);
            pl.u.z = (u32)f2bf(v[4] - bf2f(hh[4])) | ((u32)f2bf(v[5] - bf2f(hh[5])) << 16);
            pl.u.w = (u32)f2bf(v[6] - bf2f(hh[6])) | ((u32)f2bf(v[7] - bf2f(hh[7])) << 16);
            ah[mi] = ph.v;
            al[mi] = pl.v;
        }
        // prefetch next chunk's A (predicated only near the K tail)
        if (c < NCHUNK - 1) {
            int kk = (c + 1) * 32 + quad * 8;
            float4 z = make_float4(0.f, 0.f, 0.f, 0.f);
            pf[0][0] = (kk + 4 <= K_FEAT) ? *(const float4*)&row0[kk] : z;
            pf[0][1] = (kk + 8 <= K_FEAT) ? *(const float4*)&row0[kk + 4] : z;
            pf[1][0] = (kk + 4 <= K_FEAT) ? *(const float4*)&row1[kk] : z;
            pf[1][1] = (kk + 8 <= K_FEAT) ? *(const float4*)&row1[kk + 4] : z;
        }
        // W fragments: coalesced L2 loads, double-buffered across the n-loop
        const u16* wbase = Wfrag + (size_t)c * (8 * 2 * 512);
        bf16x8 wh = *(const bf16x8*)&wbase[0 * 1024 + 0 + lane * 8];
        bf16x8 wl = *(const bf16x8*)&wbase[0 * 1024 + 512 + lane * 8];
#pragma unroll
        for (int n = 0; n < 8; ++n) {
            bf16x8 whc = wh, wlc = wl;
            if (n < 7) {
                wh = *(const bf16x8*)&wbase[(n + 1) * 1024 + 0 + lane * 8];
                wl = *(const bf16x8*)&wbase[(n + 1) * 1024 + 512 + lane * 8];
            }
            // swapped operands: D[h][tok]
            acc[0][n] = __builtin_amdgcn_mfma_f32_16x16x32_bf16(whc, ah[0], acc[0][n], 0, 0, 0);
            acc[0][n] = __builtin_amdgcn_mfma_f32_16x16x32_bf16(wlc, ah[0], acc[0][n], 0, 0, 0);
            acc[0][n] = __builtin_amdgcn_mfma_f32_16x16x32_bf16(whc, al[0], acc[0][n], 0, 0, 0);
            acc[1][n] = __builtin_amdgcn_mfma_f32_16x16x32_bf16(whc, ah[1], acc[1][n], 0, 0, 0);
            acc[1][n] = __builtin_amdgcn_mfma_f32_16x16x32_bf16(wlc, ah[1], acc[1][n], 0, 0, 0);
            acc[1][n] = __builtin_amdgcn_mfma_f32_16x16x32_bf16(whc, al[1], acc[1][n], 0, 0, 0);
        }
    }

    // Epilogue: bias + ReLU (in place), packed bf16 stores.
    // Lane holds h = n*16 + quad*4 + reg, tok = tok0 + (wave*2+mi)*16 + nn.
#pragma unroll
    for (int n = 0; n < 8; ++n) {
        float4 bb = *(const float4*)&bias_s[n * 16 + quad * 4];
#pragma unroll
        for (int mi = 0; mi < 2; ++mi) {
            int tok = tok0 + (wave * 2 + mi) * 16 + nn;
            float v0 = fmaxf(acc[mi][n][0] + bb.x, 0.f);
            float v1 = fmaxf(acc[mi][n][1] + bb.y, 0.f);
            float v2 = fmaxf(acc[mi][n][2] + bb.z, 0.f);
            float v3 = fmaxf(acc[mi][n][3] + bb.w, 0.f);
            acc[mi][n][0] = v0; acc[mi][n][1] = v1;
            acc[mi][n][2] = v2; acc[mi][n][3] = v3;
            uint2 p;
            p.x = (u32)f2bf(v0) | ((u32)f2bf(v1) << 16);
            p.y = (u32)f2bf(v2) | ((u32)f2bf(v3) << 16);
            *(uint2*)&outp[(size_t)tok * H + n * 16 + quad * 4] = p;
        }
    }

    // psum: per-feature sums over the block's 128 tokens (mi-add + nn-shuffle + LDS over waves)
#pragma unroll
    for (int n = 0; n < 8; ++n) {
        float s0 = acc[0][n][0] + acc[1][n][0];
        float s1 = acc[0][n][1] + acc[1][n][1];
        float s2 = acc[0][n][2] + acc[1][n][2];
        float s3 = acc[0][n][3] + acc[1][n][3];
        s0 += __shfl_xor(s0, 1); s0 += __shfl_xor(s0, 2); s0 += __shfl_xor(s0, 4); s0 += __shfl_xor(s0, 8);
        s1 += __shfl_xor(s1, 1); s1 += __shfl_xor(s1, 2); s1 += __shfl_xor(s1, 4); s1 += __shfl_xor(s1, 8);
        s2 += __shfl_xor(s2, 1); s2 += __shfl_xor(s2, 2); s2 += __shfl_xor(s2, 4); s2 += __shfl_xor(s2, 8);
        s3 += __shfl_xor(s3, 1); s3 += __shfl_xor(s3, 2); s3 += __shfl_xor(s3, 4); s3 += __shfl_xor(s3, 8);
        if (nn == 0) {
            psum_s[wave][n * 16 + quad * 4 + 0] = s0;
            psum_s[wave][n * 16 + quad * 4 + 1] = s1;
            psum_s[wave][n * 16 + quad * 4 + 2] = s2;
            psum_s[wave][n * 16 + quad * 4 + 3] = s3;
        }
    }
    __syncthreads();
    if (tid < H)
        psum[(size_t)blk * H + tid] = psum_s[0][tid] + psum_s[1][tid]
                                    + psum_s[2][tid] + psum_s[3][tid];
}

// ---------------- Kernel 2: scores -> masked softmax -> weighted sum (R8-proven, bf16) ----
__global__ __launch_bounds__(256) void attn_kernel(
    const u16* __restrict__ ta, const u16* __restrict__ tb,
    const int* __restrict__ mask_a, const int* __restrict__ mask_b,
    const float* __restrict__ psum_a, const float* __restrict__ psum_b,
    float* __restrict__ out)
{
    int n = blockIdx.x;
    int side = 0;
    if (n >= NREV) { side = 1; n -= NREV; }

    const u16* t = side ? tb : ta;
    const int* mask = side ? mask_b : mask_a;
    const float* psum_o = side ? psum_a : psum_b;   // partial sums of the OTHER side
    float* out_vec = out + (side ? NREV * H : 0);
    float* out_w = out + 2 * NREV * H + (side ? NREV * H : 0);

    int sample = n / 10;
    int tid = threadIdx.x;

    __shared__ float score_part[128 * 17];  // [row][col-group-of-8], padded
    __shared__ float mean_s[128];
    __shared__ float w_s[128];
    __shared__ float red[4];
    __shared__ float part_out[16 * 128];

    if (tid < 128) {
        float s = 0.f;
        const float* pb = psum_o + (size_t)sample * BLKS_PER_SAMPLE * H + tid;
#pragma unroll
        for (int i = 0; i < BLKS_PER_SAMPLE; ++i) s += pb[(size_t)i * H];
        mean_s[tid] = s * (1.0f / (float)TOK_PER_SAMPLE);
    }
    __syncthreads();

    const u16* rowbase = t + (size_t)n * 128 * H;

    // Phase 1: streaming score partials; uint4 = 8 bf16 per load, coalesced.
#pragma unroll
    for (int i = 0; i < 8; ++i) {
        int q = tid + 256 * i;          // 0..2047
        int r = q >> 4;                 // row
        int c8 = q & 15;                // group of 8 features
        uint4 v = *(const uint4*)&rowbase[r * H + c8 * 8];
        const float* m = &mean_s[c8 * 8];
        float p = 0.f;
        p += bf2f((u16)(v.x & 0xffff)) * m[0];
        p += bf2f((u16)(v.x >> 16)) * m[1];
        p += bf2f((u16)(v.y & 0xffff)) * m[2];
        p += bf2f((u16)(v.y >> 16)) * m[3];
        p += bf2f((u16)(v.z & 0xffff)) * m[4];
        p += bf2f((u16)(v.z >> 16)) * m[5];
        p += bf2f((u16)(v.w & 0xffff)) * m[6];
        p += bf2f((u16)(v.w >> 16)) * m[7];
        score_part[r * 17 + c8] = p;
    }
    __syncthreads();

    // Phase 2: row sums -> masked softmax
    float logit = -1e9f;
    if (tid < 128) {
        float s = 0.f;
#pragma unroll
        for (int j = 0; j < 16; ++j) s += score_part[tid * 17 + j];
        int mv = mask[n * 128 + tid];
        logit = (mv > 0) ? s : -1e9f;
    }

    float mx = logit;
    for (int off = 32; off > 0; off >>= 1) mx = fmaxf(mx, __shfl_xor(mx, off));
    if ((tid & 63) == 0) red[tid >> 6] = mx;
    __syncthreads();
    mx = fmaxf(fmaxf(red[0], red[1]), fmaxf(red[2], red[3]));
    __syncthreads();

    float e = __expf(logit - mx);
    float ssum = e;
    for (int off = 32; off > 0; off >>= 1) ssum += __shfl_xor(ssum, off);
    if ((tid & 63) == 0) red[tid >> 6] = ssum;
    __syncthreads();
    ssum = red[0] + red[1] + red[2] + red[3];

    float w = e / ssum;
    if (tid < 128) {
        w_s[tid] = w;
        out_w[n * 128 + tid] = w;
    }
    __syncthreads();

    // Phase 3: out[d] = sum_l w_l * row_l[d] (rows L2-hot, bf16)
    int c8 = tid & 15;   // 8 features
    int lp = tid >> 4;   // 16 l-partitions
    float o[8] = {0.f, 0.f, 0.f, 0.f, 0.f, 0.f, 0.f, 0.f};
#pragma unroll
    for (int k = 0; k < 8; ++k) {
        int l = k * 16 + lp;
        float wl = w_s[l];
        uint4 v = *(const uint4*)&rowbase[l * H + c8 * 8];
        o[0] = fmaf(wl, bf2f((u16)(v.x & 0xffff)), o[0]);
        o[1] = fmaf(wl, bf2f((u16)(v.x >> 16)), o[1]);
        o[2] = fmaf(wl, bf2f((u16)(v.y & 0xffff)), o[2]);
        o[3] = fmaf(wl, bf2f((u16)(v.y >> 16)), o[3]);
        o[4] = fmaf(wl, bf2f((u16)(v.z & 0xffff)), o[4]);
        o[5] = fmaf(wl, bf2f((u16)(v.z >> 16)), o[5]);
        o[6] = fmaf(wl, bf2f((u16)(v.w & 0xffff)), o[6]);
        o[7] = fmaf(wl, bf2f((u16)(v.w >> 16)), o[7]);
    }
    *(float4*)&part_out[lp * 128 + c8 * 8] = make_float4(o[0], o[1], o[2], o[3]);
    *(float4*)&part_out[lp * 128 + c8 * 8 + 4] = make_float4(o[4], o[5], o[6], o[7]);
    __syncthreads();
    if (tid < 128) {
        float s = 0.f;
#pragma unroll
        for (int p = 0; p < 16; ++p) s += part_out[p * 128 + tid];
        out_vec[n * 128 + tid] = s;
    }
}

// ---------------- Launch ----------------
extern "C" void kernel_launch(void* const* d_in, const int* in_sizes, int n_in,
                              void* d_out, int out_size, void* d_ws, size_t ws_size,
                              hipStream_t stream)
{
    const float* seq_a = (const float*)d_in[0];
    const float* seq_b = (const float*)d_in[1];
    const int* mask_a = (const int*)d_in[2];
    const int* mask_b = (const int*)d_in[3];
    const float* W = (const float*)d_in[4];
    const float* bias = (const float*)d_in[5];
    float* out = (float*)d_out;

    u16* ta = (u16*)d_ws;                             // 40960*128 bf16
    u16* tb = ta + (size_t)NTOK * H;                  // 40960*128 bf16
    float* psum_a = (float*)(tb + (size_t)NTOK * H);  // 320*128 f32
    float* psum_b = psum_a + NREV * H;                // 320*128 f32
    u16* Wfrag = (u16*)(psum_b + NREV * H);           // 81920 bf16

    wsplit_kernel<<<(WFRAG_ELEMS + 255) / 256, 256, 0, stream>>>(W, Wfrag);
    fc_mfma_kernel<<<640, 256, 0, stream>>>(seq_a, seq_b, Wfrag, bias, ta, tb, psum_a, psum_b);
    attn_kernel<<<640, 256, 0, stream>>>(ta, tb, mask_a, mask_b, psum_a, psum_b, out);
}